// Round 5
// baseline (261.865 us; speedup 1.0000x reference)
//
#include <hip/hip_runtime.h>
#include <stdint.h>

#define COLS 4096
#define TPB  128
#define F4PT 8          // float4s per thread = (COLS/4)/TPB
#define CAP  128
#define NEGV (-1000.0f)

// monotone float->uint key: a > b  <=>  key(a) > key(b)   (no NaNs in input)
__device__ __forceinline__ uint32_t f2key(float f) {
    uint32_t u = __float_as_uint(f);
    return u ^ (uint32_t)(((int32_t)u >> 31) | (int32_t)0x80000000);
}
// exact bitwise inverse of f2key
__device__ __forceinline__ float key2f(uint32_t k) {
    uint32_t u = (k & 0x80000000u) ? (k ^ 0x80000000u) : ~k;
    return __uint_as_float(u);
}

// find bin containing the rem-th largest over hist[128*PER]; thread t owns
// bins [t*PER,(t+1)*PER), higher bin = larger. 128 threads / 2 waves.
// Writes (bin, rem_within_bin); contains 2 __syncthreads.
template <int PER>
__device__ __forceinline__ void find_bin(const uint32_t* hist, int t, int lane, int wave,
                                         uint32_t rem, volatile uint32_t* s_wsum,
                                         volatile uint32_t* s_dig, volatile uint32_t* s_rem) {
    const int base = t * PER;
    uint32_t own[PER]; uint32_t L = 0;
#pragma unroll
    for (int i = 0; i < PER; ++i) { own[i] = hist[base + i]; L += own[i]; }
    uint32_t inc = L;                       // wave-suffix-inclusive sum
#pragma unroll
    for (int d = 1; d < 64; d <<= 1) {
        uint32_t tmp = (uint32_t)__shfl_down((int)inc, d, 64);
        if (lane + d < 64) inc += tmp;
    }
    if (lane == 0) s_wsum[wave] = inc;
    __syncthreads();
    uint32_t U = inc - L;                   // count in bins above my range
    if (wave == 0) U += s_wsum[1];
    uint32_t acc = U;
#pragma unroll
    for (int i = PER - 1; i >= 0; --i) {
        uint32_t h = own[i];
        if (h && acc < rem && rem <= acc + h) { *s_dig = (uint32_t)(base + i); *s_rem = rem - acc; }
        acc += h;
    }
    __syncthreads();
}

extern "C" __global__ __launch_bounds__(TPB, 8)
void intent_dropout_kernel(const float* __restrict__ x,
                           const int* __restrict__ pp,
                           float* __restrict__ out) {
    __shared__ uint32_t s_h1[2048];
    __shared__ uint32_t s_ck[CAP], s_ci[CAP];
    __shared__ uint32_t s_grpmax[64];
    __shared__ uint32_t s_wsum[2];
    __shared__ uint32_t s_Ckey, s_dig, s_remv, s_cnt, s_cnt2, s_Tkey, s_cutIdx, s_pbtie;

    const int row  = blockIdx.x;
    const int t    = threadIdx.x;
    const int lane = t & 63;
    const int wave = t >> 6;
    const uint32_t P = (uint32_t)pp[0];      // == 64 (valid for P <= 64)

    const float4* xr   = (const float4*)(x + (size_t)row * COLS);
    float4*       orow = (float4*)(out + (size_t)row * COLS);

    // ---- phase 0: zero hist/counters; load -> keys (held in regs); group maxes ----
#pragma unroll
    for (int i = 0; i < 16; ++i) s_h1[t + TPB * i] = 0u;
    if (t == 0) { s_cnt = 0u; s_cnt2 = 0u; }

    uint32_t keys[32];
#pragma unroll
    for (int j = 0; j < F4PT; ++j) {
        float4 v = xr[t + TPB * j];
        keys[4*j+0] = f2key(v.x); keys[4*j+1] = f2key(v.y);
        keys[4*j+2] = f2key(v.z); keys[4*j+3] = f2key(v.w);
        // 64 disjoint groups of 64 elems: group = (t>>4) + 8*j
        uint32_t m = max(max(keys[4*j], keys[4*j+1]), max(keys[4*j+2], keys[4*j+3]));
#pragma unroll
        for (int d = 1; d < 16; d <<= 1) m = max(m, (uint32_t)__shfl_xor((int)m, d, 64));
        if ((lane & 15) == 0) s_grpmax[(t >> 4) + 8 * j] = m;
    }
    __syncthreads();                                            // B1
    if (t < 64) {   // C = min of group maxes  =>  >= 64 elems >= C
        uint32_t g = s_grpmax[t];
#pragma unroll
        for (int d = 1; d < 64; d <<= 1) g = min(g, (uint32_t)__shfl_xor((int)g, d, 64));
        if (t == 0) s_Ckey = g;
    }
    __syncthreads();                                            // B2
    const uint32_t Ckey = s_Ckey;

    // ---- level-1 hist of candidates on bits [31:21] ----
#pragma unroll
    for (int i = 0; i < 32; ++i)
        if (keys[i] >= Ckey) atomicAdd(&s_h1[keys[i] >> 21], 1u);
    __syncthreads();                                            // B3
    find_bin<16>(s_h1, t, lane, wave, P, s_wsum, &s_dig, &s_remv);   // B4,B5
    const uint32_t d1 = s_dig, rem1 = s_remv;

    // ---- compact bin-d1 candidates (key,idx); typically ~20-60 entries ----
#pragma unroll
    for (int j = 0; j < F4PT; ++j) {
#pragma unroll
        for (int c = 0; c < 4; ++c) {
            uint32_t k = keys[4*j+c];
            if (k >= Ckey && (k >> 21) == d1) {
                uint32_t s = atomicAdd(&s_cnt, 1u);
                if (s < CAP) { s_ck[s] = k; s_ci[s] = (uint32_t)(4*(t + TPB*j) + c); }
            }
        }
    }
    __syncthreads();                                            // B6
    const uint32_t cnt = s_cnt;

    if (cnt <= CAP) {
        // ---- single-wave exact rank-select over <=128 entries ----
        // order: key desc, idx asc. boundary entry rank == rem1-1 gives
        // (Tkey, cutIdx); kill rule is then purely elementwise.
        if (t < 64) {
            uint32_t ka = 0, ia = 0, kb = 0, ib = 0;
            const bool ha = (uint32_t)t < cnt, hb = (uint32_t)(t + 64) < cnt;
            if (ha) { ka = s_ck[t];      ia = s_ci[t]; }
            if (hb) { kb = s_ck[t + 64]; ib = s_ci[t + 64]; }
            uint32_t ra = 0, rb = 0;
            for (uint32_t e = 0; e < cnt; ++e) {
                uint32_t ke = s_ck[e], ie = s_ci[e];
                ra += (uint32_t)((ke > ka) || (ke == ka && ie < ia));
                rb += (uint32_t)((ke > kb) || (ke == kb && ie < ib));
            }
            if (ha && ra == rem1 - 1u) { s_Tkey = ka; s_cutIdx = ia; }
            if (hb && rb == rem1 - 1u) { s_Tkey = kb; s_cutIdx = ib; }
        }
        __syncthreads();                                        // B7
    } else {
        // ================= exact fallback (unreachable on N(0,1) data) =========
        // level 2: bits [20:10] within bin d1
#pragma unroll
        for (int i = 0; i < 16; ++i) s_h1[t + TPB * i] = 0u;
        __syncthreads();
#pragma unroll
        for (int i = 0; i < 32; ++i) {
            uint32_t k = keys[i];
            if (k >= Ckey && (k >> 21) == d1) atomicAdd(&s_h1[(k >> 10) & 0x7FFu], 1u);
        }
        __syncthreads();
        find_bin<16>(s_h1, t, lane, wave, rem1, s_wsum, &s_dig, &s_remv);
        const uint32_t d2 = s_dig, rem2 = s_remv;
        const uint32_t pre21 = (d1 << 11) | d2;
        // compact-2
#pragma unroll
        for (int j = 0; j < F4PT; ++j) {
#pragma unroll
            for (int c = 0; c < 4; ++c) {
                uint32_t k = keys[4*j+c];
                if (k >= Ckey && (k >> 10) == pre21) {
                    uint32_t s = atomicAdd(&s_cnt2, 1u);
                    if (s < CAP) { s_ck[s] = k; s_ci[s] = (uint32_t)(4*(t + TPB*j) + c); }
                }
            }
        }
        __syncthreads();
        const uint32_t cnt2 = s_cnt2;
        if (cnt2 <= CAP) {
            if (t < 64) {
                uint32_t ka = 0, ia = 0, kb = 0, ib = 0;
                const bool ha = (uint32_t)t < cnt2, hb = (uint32_t)(t + 64) < cnt2;
                if (ha) { ka = s_ck[t];      ia = s_ci[t]; }
                if (hb) { kb = s_ck[t + 64]; ib = s_ci[t + 64]; }
                uint32_t ra = 0, rb = 0;
                for (uint32_t e = 0; e < cnt2; ++e) {
                    uint32_t ke = s_ck[e], ie = s_ci[e];
                    ra += (uint32_t)((ke > ka) || (ke == ka && ie < ia));
                    rb += (uint32_t)((ke > kb) || (ke == kb && ie < ib));
                }
                if (ha && ra == rem2 - 1u) { s_Tkey = ka; s_cutIdx = ia; }
                if (hb && rb == rem2 - 1u) { s_Tkey = kb; s_cutIdx = ib; }
            }
            __syncthreads();
        } else {
            // level 3: bits [9:0] -> exact Tkey
#pragma unroll
            for (int i = 0; i < 16; ++i) s_h1[t + TPB * i] = 0u;
            __syncthreads();
#pragma unroll
            for (int i = 0; i < 32; ++i) {
                uint32_t k = keys[i];
                if (k >= Ckey && (k >> 10) == pre21) atomicAdd(&s_h1[k & 0x3FFu], 1u);
            }
            __syncthreads();
            find_bin<8>(s_h1, t, lane, wave, rem2, s_wsum, &s_dig, &s_remv);
            const uint32_t Tk  = (pre21 << 10) | s_dig;
            const uint32_t keq = s_remv;          // #ties to kill (smallest idx first)
            // cutIdx via reversed idx-pair bins: rev bin = 2047-(idx>>1)
#pragma unroll
            for (int i = 0; i < 16; ++i) s_h1[t + TPB * i] = 0u;
            __syncthreads();
#pragma unroll
            for (int j = 0; j < F4PT; ++j)
#pragma unroll
                for (int c = 0; c < 4; ++c)
                    if (keys[4*j+c] == Tk)
                        atomicAdd(&s_h1[2047u - ((uint32_t)(4*(t + TPB*j) + c) >> 1)], 1u);
            __syncthreads();
            find_bin<16>(s_h1, t, lane, wave, keq, s_wsum, &s_dig, &s_remv);
            const uint32_t br = s_dig, remv = s_remv;
            const uint32_t pairBase = 2u * (2047u - br);
            {   // owner of elem pairBase reports whether it's a tie
                const uint32_t f = pairBase >> 2;             // float4 index
                if ((uint32_t)t == (f & (uint32_t)(TPB - 1))) {
                    const uint32_t jj = f >> 7, cc = pairBase & 3u;
                    s_pbtie = (uint32_t)(keys[4*jj + cc] == Tk);
                }
            }
            __syncthreads();
            if (t == 0) {
                const uint32_t cp = s_h1[br];                 // ties in this pair (1 or 2)
                uint32_t cut;
                if (cp >= 2u) cut = (remv == 1u) ? pairBase : pairBase + 1u;
                else          cut = s_pbtie ? pairBase : pairBase + 1u;
                s_Tkey = Tk; s_cutIdx = cut;
            }
            __syncthreads();
        }
    }

    // ---- masked write: kill iff key > Tkey || (key == Tkey && idx <= cutIdx) ----
    const uint32_t Tkey = s_Tkey, cutIdx = s_cutIdx;
#pragma unroll
    for (int j = 0; j < F4PT; ++j) {
        float4 o;
        float* c4 = (float*)&o;
#pragma unroll
        for (int c = 0; c < 4; ++c) {
            const uint32_t k   = keys[4*j+c];
            const uint32_t idx = (uint32_t)(4*(t + TPB*j) + c);
            const bool kill = (k > Tkey) || (k == Tkey && idx <= cutIdx);
            c4[c] = kill ? NEGV : key2f(k);
        }
        orow[t + TPB * j] = o;
    }
}

extern "C" void kernel_launch(void* const* d_in, const int* in_sizes, int n_in,
                              void* d_out, int out_size, void* d_ws, size_t ws_size,
                              hipStream_t stream) {
    const float* x   = (const float*)d_in[0];
    const int*   pp  = (const int*)d_in[1];
    float*       out = (float*)d_out;
    int rows = in_sizes[0] / COLS;           // 8192
    hipLaunchKernelGGL(intent_dropout_kernel, dim3(rows), dim3(TPB), 0, stream,
                       x, pp, out);
}

// Round 6
// 242.751 us; speedup vs baseline: 1.0787x; 1.0787x over previous
//
#include <hip/hip_runtime.h>
#include <stdint.h>

#define COLS 4096
#define TPB  256
#define F4PT 4          // float4s per thread = (COLS/4)/TPB
#define CAP  128
#define NEGV (-1000.0f)

// monotone float->uint key: a > b  <=>  key(a) > key(b)   (no NaNs in input)
__device__ __forceinline__ uint32_t f2key(float f) {
    uint32_t u = __float_as_uint(f);
    return u ^ (uint32_t)(((int32_t)u >> 31) | (int32_t)0x80000000);
}
// exact bitwise inverse of f2key
__device__ __forceinline__ float key2f(uint32_t k) {
    uint32_t u = (k & 0x80000000u) ? (k ^ 0x80000000u) : ~k;
    return __uint_as_float(u);
}

// find bin containing the rem-th largest over hist[256*PER]; thread t owns
// bins [t*PER,(t+1)*PER), higher bin = larger. 256 threads / 4 waves.
// Writes (bin, rem_within_bin); contains 2 __syncthreads.
template <int PER>
__device__ __forceinline__ void find_bin(const uint32_t* hist, int t, int lane, int wave,
                                         uint32_t rem, volatile uint32_t* s_wsum,
                                         volatile uint32_t* s_dig, volatile uint32_t* s_rem) {
    const int base = t * PER;
    uint32_t own[PER]; uint32_t L = 0;
#pragma unroll
    for (int i = 0; i < PER; ++i) { own[i] = hist[base + i]; L += own[i]; }
    uint32_t inc = L;                       // wave-suffix-inclusive sum
#pragma unroll
    for (int d = 1; d < 64; d <<= 1) {
        uint32_t tmp = (uint32_t)__shfl_down((int)inc, d, 64);
        if (lane + d < 64) inc += tmp;
    }
    if (lane == 0) s_wsum[wave] = inc;
    __syncthreads();
    uint32_t U = inc - L;                   // count in bins above my range
#pragma unroll
    for (int w = 1; w < 4; ++w) if (wave + w < 4) U += s_wsum[wave + w];
    uint32_t acc = U;
#pragma unroll
    for (int i = PER - 1; i >= 0; --i) {
        uint32_t h = own[i];
        if (h && acc < rem && rem <= acc + h) { *s_dig = (uint32_t)(base + i); *s_rem = rem - acc; }
        acc += h;
    }
    __syncthreads();
}

extern "C" __global__ __launch_bounds__(TPB, 8)
void intent_dropout_kernel(const float* __restrict__ x,
                           const int* __restrict__ pp,
                           float* __restrict__ out) {
    __shared__ uint32_t s_h1[2048];
    __shared__ uint32_t s_ck[CAP], s_ci[CAP];
    __shared__ uint32_t s_grpmax[64];
    __shared__ uint32_t s_wsum[4];
    __shared__ uint32_t s_Ckey, s_dig, s_remv, s_cnt, s_cnt2, s_Tkey, s_cutIdx, s_pbtie;

    const int row  = blockIdx.x;
    const int t    = threadIdx.x;
    const int lane = t & 63;
    const int wave = t >> 6;
    const uint32_t P = (uint32_t)pp[0];      // == 64 (valid for P <= 64)

    const float4* xr   = (const float4*)(x + (size_t)row * COLS);
    float4*       orow = (float4*)(out + (size_t)row * COLS);

    // ---- phase 0: zero hist/counters; load -> keys (regs, 16 = no spill); grp maxes ----
#pragma unroll
    for (int i = 0; i < 8; ++i) s_h1[t + TPB * i] = 0u;
    if (t == 0) { s_cnt = 0u; s_cnt2 = 0u; }

    uint32_t keys[16];
#pragma unroll
    for (int j = 0; j < F4PT; ++j) {
        float4 v = xr[t + TPB * j];
        keys[4*j+0] = f2key(v.x); keys[4*j+1] = f2key(v.y);
        keys[4*j+2] = f2key(v.z); keys[4*j+3] = f2key(v.w);
        // 64 disjoint groups of 64 elems: group = (t>>4) + 16*j
        uint32_t m = max(max(keys[4*j], keys[4*j+1]), max(keys[4*j+2], keys[4*j+3]));
#pragma unroll
        for (int d = 1; d < 16; d <<= 1) m = max(m, (uint32_t)__shfl_xor((int)m, d, 64));
        if ((lane & 15) == 0) s_grpmax[(t >> 4) + 16 * j] = m;
    }
    __syncthreads();                                            // B1
    if (t < 64) {   // C = min of group maxes  =>  >= 64 elems >= C
        uint32_t g = s_grpmax[t];
#pragma unroll
        for (int d = 1; d < 64; d <<= 1) g = min(g, (uint32_t)__shfl_xor((int)g, d, 64));
        if (t == 0) s_Ckey = g;
    }
    __syncthreads();                                            // B2
    const uint32_t Ckey = s_Ckey;

    // ---- level-1 hist of candidates on bits [31:21] ----
#pragma unroll
    for (int i = 0; i < 16; ++i)
        if (keys[i] >= Ckey) atomicAdd(&s_h1[keys[i] >> 21], 1u);
    __syncthreads();                                            // B3
    find_bin<8>(s_h1, t, lane, wave, P, s_wsum, &s_dig, &s_remv);    // B4,B5
    const uint32_t d1 = s_dig, rem1 = s_remv;

    // ---- compact bin-d1 candidates (key,idx); typically ~5-60 entries ----
#pragma unroll
    for (int j = 0; j < F4PT; ++j) {
#pragma unroll
        for (int c = 0; c < 4; ++c) {
            uint32_t k = keys[4*j+c];
            if (k >= Ckey && (k >> 21) == d1) {
                uint32_t s = atomicAdd(&s_cnt, 1u);
                if (s < CAP) { s_ck[s] = k; s_ci[s] = (uint32_t)(4*(t + TPB*j) + c); }
            }
        }
    }
    __syncthreads();                                            // B6
    const uint32_t cnt = s_cnt;

    if (cnt <= CAP) {
        // ---- single-wave exact rank-select over <=128 entries ----
        // total order: key desc, idx asc. entry with rank rem1-1 is the last
        // killed element -> (Tkey, cutIdx); kill rule becomes elementwise.
        if (t < 64) {
            uint32_t ka = 0, ia = 0, kb = 0, ib = 0;
            const bool ha = (uint32_t)t < cnt, hb = (uint32_t)(t + 64) < cnt;
            if (ha) { ka = s_ck[t];      ia = s_ci[t]; }
            if (hb) { kb = s_ck[t + 64]; ib = s_ci[t + 64]; }
            uint32_t ra = 0, rb = 0;
            for (uint32_t e = 0; e < cnt; ++e) {
                uint32_t ke = s_ck[e], ie = s_ci[e];
                ra += (uint32_t)((ke > ka) || (ke == ka && ie < ia));
                rb += (uint32_t)((ke > kb) || (ke == kb && ie < ib));
            }
            if (ha && ra == rem1 - 1u) { s_Tkey = ka; s_cutIdx = ia; }
            if (hb && rb == rem1 - 1u) { s_Tkey = kb; s_cutIdx = ib; }
        }
        __syncthreads();                                        // B7
    } else {
        // ================= exact fallback (unreachable on N(0,1) data) =========
        // level 2: bits [20:10] within bin d1
#pragma unroll
        for (int i = 0; i < 8; ++i) s_h1[t + TPB * i] = 0u;
        __syncthreads();
#pragma unroll
        for (int i = 0; i < 16; ++i) {
            uint32_t k = keys[i];
            if (k >= Ckey && (k >> 21) == d1) atomicAdd(&s_h1[(k >> 10) & 0x7FFu], 1u);
        }
        __syncthreads();
        find_bin<8>(s_h1, t, lane, wave, rem1, s_wsum, &s_dig, &s_remv);
        const uint32_t d2 = s_dig, rem2 = s_remv;
        const uint32_t pre21 = (d1 << 11) | d2;
        // compact-2
#pragma unroll
        for (int j = 0; j < F4PT; ++j) {
#pragma unroll
            for (int c = 0; c < 4; ++c) {
                uint32_t k = keys[4*j+c];
                if (k >= Ckey && (k >> 10) == pre21) {
                    uint32_t s = atomicAdd(&s_cnt2, 1u);
                    if (s < CAP) { s_ck[s] = k; s_ci[s] = (uint32_t)(4*(t + TPB*j) + c); }
                }
            }
        }
        __syncthreads();
        const uint32_t cnt2 = s_cnt2;
        if (cnt2 <= CAP) {
            if (t < 64) {
                uint32_t ka = 0, ia = 0, kb = 0, ib = 0;
                const bool ha = (uint32_t)t < cnt2, hb = (uint32_t)(t + 64) < cnt2;
                if (ha) { ka = s_ck[t];      ia = s_ci[t]; }
                if (hb) { kb = s_ck[t + 64]; ib = s_ci[t + 64]; }
                uint32_t ra = 0, rb = 0;
                for (uint32_t e = 0; e < cnt2; ++e) {
                    uint32_t ke = s_ck[e], ie = s_ci[e];
                    ra += (uint32_t)((ke > ka) || (ke == ka && ie < ia));
                    rb += (uint32_t)((ke > kb) || (ke == kb && ie < ib));
                }
                if (ha && ra == rem2 - 1u) { s_Tkey = ka; s_cutIdx = ia; }
                if (hb && rb == rem2 - 1u) { s_Tkey = kb; s_cutIdx = ib; }
            }
            __syncthreads();
        } else {
            // level 3: bits [9:0] -> exact Tkey
#pragma unroll
            for (int i = 0; i < 8; ++i) s_h1[t + TPB * i] = 0u;
            __syncthreads();
#pragma unroll
            for (int i = 0; i < 16; ++i) {
                uint32_t k = keys[i];
                if (k >= Ckey && (k >> 10) == pre21) atomicAdd(&s_h1[k & 0x3FFu], 1u);
            }
            __syncthreads();
            find_bin<4>(s_h1, t, lane, wave, rem2, s_wsum, &s_dig, &s_remv);
            const uint32_t Tk  = (pre21 << 10) | s_dig;
            const uint32_t keq = s_remv;          // #ties to kill (smallest idx first)
            // cutIdx via reversed idx-pair bins: rev bin = 2047-(idx>>1)
#pragma unroll
            for (int i = 0; i < 8; ++i) s_h1[t + TPB * i] = 0u;
            __syncthreads();
#pragma unroll
            for (int j = 0; j < F4PT; ++j)
#pragma unroll
                for (int c = 0; c < 4; ++c)
                    if (keys[4*j+c] == Tk)
                        atomicAdd(&s_h1[2047u - ((uint32_t)(4*(t + TPB*j) + c) >> 1)], 1u);
            __syncthreads();
            find_bin<8>(s_h1, t, lane, wave, keq, s_wsum, &s_dig, &s_remv);
            const uint32_t br = s_dig, remv = s_remv;
            const uint32_t pairBase = 2u * (2047u - br);
            {   // owner of elem pairBase reports whether it's a tie
                const uint32_t f = pairBase >> 2;             // float4 index
                if ((uint32_t)t == (f & (uint32_t)(TPB - 1))) {
                    const uint32_t jj = f >> 8, cc = pairBase & 3u;
                    s_pbtie = (uint32_t)(keys[4*jj + cc] == Tk);
                }
            }
            __syncthreads();
            if (t == 0) {
                const uint32_t cp = s_h1[br];                 // ties in this pair (1 or 2)
                uint32_t cut;
                if (cp >= 2u) cut = (remv == 1u) ? pairBase : pairBase + 1u;
                else          cut = s_pbtie ? pairBase : pairBase + 1u;
                s_Tkey = Tk; s_cutIdx = cut;
            }
            __syncthreads();
        }
    }

    // ---- masked write: kill iff key > Tkey || (key == Tkey && idx <= cutIdx) ----
    const uint32_t Tkey = s_Tkey, cutIdx = s_cutIdx;
#pragma unroll
    for (int j = 0; j < F4PT; ++j) {
        float4 o;
        float* c4 = (float*)&o;
#pragma unroll
        for (int c = 0; c < 4; ++c) {
            const uint32_t k   = keys[4*j+c];
            const uint32_t idx = (uint32_t)(4*(t + TPB*j) + c);
            const bool kill = (k > Tkey) || (k == Tkey && idx <= cutIdx);
            c4[c] = kill ? NEGV : key2f(k);
        }
        orow[t + TPB * j] = o;
    }
}

extern "C" void kernel_launch(void* const* d_in, const int* in_sizes, int n_in,
                              void* d_out, int out_size, void* d_ws, size_t ws_size,
                              hipStream_t stream) {
    const float* x   = (const float*)d_in[0];
    const int*   pp  = (const int*)d_in[1];
    float*       out = (float*)d_out;
    int rows = in_sizes[0] / COLS;           // 8192
    hipLaunchKernelGGL(intent_dropout_kernel, dim3(rows), dim3(TPB), 0, stream,
                       x, pp, out);
}

// Round 10
// 236.750 us; speedup vs baseline: 1.1061x; 1.0253x over previous
//
#include <hip/hip_runtime.h>
#include <stdint.h>

#define COLS 4096
#define TPB  256
#define CAP  128
#define NEGV (-1000.0f)

// monotone float->uint key: a > b  <=>  key(a) > key(b)   (no NaNs in input)
__device__ __forceinline__ uint32_t f2key(float f) {
    uint32_t u = __float_as_uint(f);
    return u ^ (uint32_t)(((int32_t)u >> 31) | (int32_t)0x80000000);
}
// exact bitwise inverse of f2key
__device__ __forceinline__ float key2f(uint32_t k) {
    uint32_t u = (k & 0x80000000u) ? (k ^ 0x80000000u) : ~k;
    return __uint_as_float(u);
}

// unpacked find_bin over 2048-bin hist (256 thr, 8 bins/thr): bin holding the
// rem-th largest. 2 internal __syncthreads. Caller must barrier after hist fill.
__device__ __forceinline__ void find_bin8(const uint32_t* hist, int t, int lane, int wave,
                                          uint32_t rem, uint32_t* s_wsum,
                                          uint32_t* s_dig, uint32_t* s_rem) {
    const int base = t * 8;
    uint32_t own[8]; uint32_t L = 0;
#pragma unroll
    for (int i = 0; i < 8; ++i) { own[i] = hist[base + i]; L += own[i]; }
    uint32_t inc = L;
#pragma unroll
    for (int d = 1; d < 64; d <<= 1) {
        uint32_t tmp = (uint32_t)__shfl_down((int)inc, d, 64);
        if (lane + d < 64) inc += tmp;
    }
    if (lane == 0) s_wsum[wave] = inc;
    __syncthreads();
    uint32_t U = inc - L;
#pragma unroll
    for (int w = 1; w < 4; ++w) if (wave + w < 4) U += s_wsum[wave + w];
    uint32_t acc = U;
#pragma unroll
    for (int i = 7; i >= 0; --i) {
        uint32_t h = own[i];
        if (h && acc < rem && rem <= acc + h) { *s_dig = (uint32_t)(base + i); *s_rem = rem - acc; }
        acc += h;
    }
    __syncthreads();
}

// one wave: exact rank-select over cnt<=128 (key,idx) entries; order key desc, idx asc.
// entry with rank rem-1 = last killed -> (Tkey, cutIdx).
__device__ __forceinline__ void rank_select(const uint32_t* ck, const uint32_t* ci,
                                            uint32_t cnt, uint32_t rem, int lane,
                                            uint32_t* tkey, uint32_t* cut) {
    uint32_t ka = 0, ia = 0, kb = 0, ib = 0;
    const bool ha = (uint32_t)lane < cnt, hb = (uint32_t)(lane + 64) < cnt;
    if (ha) { ka = ck[lane];      ia = ci[lane]; }
    if (hb) { kb = ck[lane + 64]; ib = ci[lane + 64]; }
    uint32_t ra = 0, rb = 0;
    for (uint32_t e = 0; e < cnt; ++e) {
        uint32_t ke = ck[e], ie = ci[e];
        ra += (uint32_t)((ke > ka) || (ke == ka && ie < ia));
        rb += (uint32_t)((ke > kb) || (ke == kb && ie < ib));
    }
    if (ha && ra == rem - 1u) { *tkey = ka; *cut = ia; }
    if (hb && rb == rem - 1u) { *tkey = kb; *cut = ib; }
}

// exact multi-level fallback for one row (cold; only if level-1 bin > CAP entries)
__device__ void solve_row_cold(const uint32_t (&k)[16], uint32_t d1, uint32_t rem1,
                               uint32_t* s_h, uint32_t* s_ck, uint32_t* s_ci,
                               uint32_t* s_wsum, uint32_t* s_dig, uint32_t* s_remv,
                               uint32_t* s_cnt2, uint32_t* s_pbtie,
                               uint32_t* tkey, uint32_t* cut,
                               int t, int lane, int wave) {
    // level 2: bits [20:10] within bin d1
#pragma unroll
    for (int i = 0; i < 8; ++i) s_h[t + TPB * i] = 0u;
    if (t == 0) *s_cnt2 = 0u;
    __syncthreads();
#pragma unroll
    for (int i = 0; i < 16; ++i)
        if ((k[i] >> 21) == d1) atomicAdd(&s_h[(k[i] >> 10) & 0x7FFu], 1u);
    __syncthreads();
    find_bin8(s_h, t, lane, wave, rem1, s_wsum, s_dig, s_remv);
    const uint32_t d2 = *s_dig, rem2 = *s_remv;
    const uint32_t pre21 = (d1 << 11) | d2;
#pragma unroll
    for (int j = 0; j < 4; ++j)
#pragma unroll
        for (int c = 0; c < 4; ++c) {
            uint32_t kk = k[4 * j + c];
            if ((kk >> 10) == pre21) {
                uint32_t s = atomicAdd(s_cnt2, 1u);
                if (s < CAP) { s_ck[s] = kk; s_ci[s] = (uint32_t)(4 * (t + TPB * j) + c); }
            }
        }
    __syncthreads();
    const uint32_t cnt2 = *s_cnt2;
    if (cnt2 <= CAP) {
        if (wave == 0) rank_select(s_ck, s_ci, cnt2, rem2, lane, tkey, cut);
        __syncthreads();
        return;
    }
    // level 3: bits [9:0] -> exact Tkey + tie count
#pragma unroll
    for (int i = 0; i < 8; ++i) s_h[t + TPB * i] = 0u;
    __syncthreads();
#pragma unroll
    for (int i = 0; i < 16; ++i)
        if ((k[i] >> 10) == pre21) atomicAdd(&s_h[k[i] & 0x3FFu], 1u);
    __syncthreads();
    find_bin8(s_h, t, lane, wave, rem2, s_wsum, s_dig, s_remv);
    const uint32_t Tk = (pre21 << 10) | *s_dig;
    const uint32_t keq = *s_remv;               // #ties to kill (smallest idx first)
    // cutIdx via reversed idx-pair bins: rev bin = 2047-(idx>>1)
#pragma unroll
    for (int i = 0; i < 8; ++i) s_h[t + TPB * i] = 0u;
    __syncthreads();
#pragma unroll
    for (int j = 0; j < 4; ++j)
#pragma unroll
        for (int c = 0; c < 4; ++c)
            if (k[4 * j + c] == Tk)
                atomicAdd(&s_h[2047u - ((uint32_t)(4 * (t + TPB * j) + c) >> 1)], 1u);
    __syncthreads();
    find_bin8(s_h, t, lane, wave, keq, s_wsum, s_dig, s_remv);
    const uint32_t br = *s_dig, remv = *s_remv;
    const uint32_t pairBase = 2u * (2047u - br);
    {   // owner of elem pairBase reports whether it's a tie (static-index select)
        const uint32_t f = pairBase >> 2;
        if ((uint32_t)t == (f & (uint32_t)(TPB - 1))) {
            const int sel = (int)(4u * (f >> 8) + (pairBase & 3u));
            uint32_t kv = 0;
#pragma unroll
            for (int q = 0; q < 16; ++q) if (q == sel) kv = k[q];
            *s_pbtie = (uint32_t)(kv == Tk);
        }
    }
    __syncthreads();
    if (t == 0) {
        const uint32_t cp = s_h[br];
        uint32_t cu;
        if (cp >= 2u) cu = (remv == 1u) ? pairBase : pairBase + 1u;
        else          cu = (*s_pbtie) ? pairBase : pairBase + 1u;
        *tkey = Tk; *cut = cu;
    }
    __syncthreads();
}

extern "C" __global__ __launch_bounds__(TPB, 4)
void intent_dropout_kernel(const float* __restrict__ x,
                           const int* __restrict__ pp,
                           float* __restrict__ out) {
    __shared__ uint32_t s_h[2048];                 // packed hist: row0 lo16, row1 hi16
    __shared__ uint32_t s_ck0[CAP], s_ci0[CAP];
    __shared__ uint32_t s_ck1[CAP], s_ci1[CAP];
    __shared__ uint32_t s_wsum[4];
    __shared__ uint32_t s_cnt0, s_cnt1, s_cnt2, s_pbtie;
    __shared__ uint32_t s_d[2], s_r[2];
    __shared__ uint32_t s_Tk[2], s_cut[2];
    __shared__ uint32_t s_dig, s_remv;

    const int t = threadIdx.x, lane = t & 63, wave = t >> 6;
    const uint32_t P = (uint32_t)pp[0];            // == 64 (valid for P <= 64)
    const int row0 = blockIdx.x * 2;

    const float4* x0 = (const float4*)(x + (size_t)row0 * COLS);
    const float4* x1 = (const float4*)(x + (size_t)(row0 + 1) * COLS);
    float4* o0 = (float4*)(out + (size_t)row0 * COLS);
    float4* o1 = (float4*)(out + (size_t)(row0 + 1) * COLS);

    // ---- zero hist/counters; load both rows -> keys in regs ----
#pragma unroll
    for (int i = 0; i < 8; ++i) s_h[t + TPB * i] = 0u;
    if (t == 0) { s_cnt0 = 0u; s_cnt1 = 0u; }

    uint32_t k0[16], k1[16];
#pragma unroll
    for (int j = 0; j < 4; ++j) {
        float4 v = x0[t + TPB * j];
        k0[4*j+0] = f2key(v.x); k0[4*j+1] = f2key(v.y);
        k0[4*j+2] = f2key(v.z); k0[4*j+3] = f2key(v.w);
    }
#pragma unroll
    for (int j = 0; j < 4; ++j) {
        float4 v = x1[t + TPB * j];
        k1[4*j+0] = f2key(v.x); k1[4*j+1] = f2key(v.y);
        k1[4*j+2] = f2key(v.z); k1[4*j+3] = f2key(v.w);
    }
    __syncthreads();                                            // B1

    // ---- packed level-1 hist on bits [31:21], both rows in one array ----
#pragma unroll
    for (int i = 0; i < 16; ++i) atomicAdd(&s_h[k0[i] >> 21], 1u);
#pragma unroll
    for (int i = 0; i < 16; ++i) atomicAdd(&s_h[k1[i] >> 21], 0x10000u);
    __syncthreads();                                            // B2

    // ---- packed find_bin: ONE scan chain resolves both rows ----
    {
        const int base = t * 8;
        uint32_t own[8]; uint32_t L = 0;
#pragma unroll
        for (int i = 0; i < 8; ++i) { own[i] = s_h[base + i]; L += own[i]; }
        uint32_t inc = L;                     // per-field sums <= 4096, no overflow
#pragma unroll
        for (int d = 1; d < 64; d <<= 1) {
            uint32_t tmp = (uint32_t)__shfl_down((int)inc, d, 64);
            if (lane + d < 64) inc += tmp;
        }
        if (lane == 0) s_wsum[wave] = inc;
        __syncthreads();                                        // B3
        uint32_t U = inc - L;
#pragma unroll
        for (int w = 1; w < 4; ++w) if (wave + w < 4) U += s_wsum[wave + w];
        uint32_t a0 = U & 0xFFFFu, a1 = U >> 16;
#pragma unroll
        for (int i = 7; i >= 0; --i) {
            uint32_t h0 = own[i] & 0xFFFFu, h1 = own[i] >> 16;
            if (h0 && a0 < P && P <= a0 + h0) { s_d[0] = (uint32_t)(base + i); s_r[0] = P - a0; }
            if (h1 && a1 < P && P <= a1 + h1) { s_d[1] = (uint32_t)(base + i); s_r[1] = P - a1; }
            a0 += h0; a1 += h1;
        }
        __syncthreads();                                        // B4
    }
    const uint32_t d1_0 = s_d[0], r1_0 = s_r[0];
    const uint32_t d1_1 = s_d[1], r1_1 = s_r[1];

    // ---- compact level-1 bin candidates per row ----
#pragma unroll
    for (int j = 0; j < 4; ++j)
#pragma unroll
        for (int c = 0; c < 4; ++c) {
            uint32_t kk = k0[4*j+c];
            if ((kk >> 21) == d1_0) {
                uint32_t s = atomicAdd(&s_cnt0, 1u);
                if (s < CAP) { s_ck0[s] = kk; s_ci0[s] = (uint32_t)(4*(t + TPB*j) + c); }
            }
        }
#pragma unroll
    for (int j = 0; j < 4; ++j)
#pragma unroll
        for (int c = 0; c < 4; ++c) {
            uint32_t kk = k1[4*j+c];
            if ((kk >> 21) == d1_1) {
                uint32_t s = atomicAdd(&s_cnt1, 1u);
                if (s < CAP) { s_ck1[s] = kk; s_ci1[s] = (uint32_t)(4*(t + TPB*j) + c); }
            }
        }
    __syncthreads();                                            // B5
    const uint32_t c0 = s_cnt0, c1 = s_cnt1;

    if (c0 <= CAP && c1 <= CAP) {
        // both rows' rank-selects run CONCURRENTLY on wave0/wave1
        if (wave == 0)      rank_select(s_ck0, s_ci0, c0, r1_0, lane, &s_Tk[0], &s_cut[0]);
        else if (wave == 1) rank_select(s_ck1, s_ci1, c1, r1_1, lane, &s_Tk[1], &s_cut[1]);
        __syncthreads();                                        // B6
    } else {
        // cold exact path, per row sequentially
        if (c0 <= CAP) {
            if (wave == 0) rank_select(s_ck0, s_ci0, c0, r1_0, lane, &s_Tk[0], &s_cut[0]);
            __syncthreads();
        } else {
            solve_row_cold(k0, d1_0, r1_0, s_h, s_ck0, s_ci0, s_wsum, &s_dig, &s_remv,
                           &s_cnt2, &s_pbtie, &s_Tk[0], &s_cut[0], t, lane, wave);
        }
        if (c1 <= CAP) {
            if (wave == 0) rank_select(s_ck1, s_ci1, c1, r1_1, lane, &s_Tk[1], &s_cut[1]);
            __syncthreads();
        } else {
            solve_row_cold(k1, d1_1, r1_1, s_h, s_ck1, s_ci1, s_wsum, &s_dig, &s_remv,
                           &s_cnt2, &s_pbtie, &s_Tk[1], &s_cut[1], t, lane, wave);
        }
    }

    // ---- masked write: kill iff key > Tkey || (key == Tkey && idx <= cutIdx) ----
    {
        const uint32_t T0 = s_Tk[0], X0 = s_cut[0];
#pragma unroll
        for (int j = 0; j < 4; ++j) {
            float4 o; float* c4 = (float*)&o;
#pragma unroll
            for (int c = 0; c < 4; ++c) {
                uint32_t kk = k0[4*j+c];
                uint32_t idx = (uint32_t)(4*(t + TPB*j) + c);
                c4[c] = ((kk > T0) || (kk == T0 && idx <= X0)) ? NEGV : key2f(kk);
            }
            o0[t + TPB * j] = o;
        }
        const uint32_t T1 = s_Tk[1], X1 = s_cut[1];
#pragma unroll
        for (int j = 0; j < 4; ++j) {
            float4 o; float* c4 = (float*)&o;
#pragma unroll
            for (int c = 0; c < 4; ++c) {
                uint32_t kk = k1[4*j+c];
                uint32_t idx = (uint32_t)(4*(t + TPB*j) + c);
                c4[c] = ((kk > T1) || (kk == T1 && idx <= X1)) ? NEGV : key2f(kk);
            }
            o1[t + TPB * j] = o;
        }
    }
}

extern "C" void kernel_launch(void* const* d_in, const int* in_sizes, int n_in,
                              void* d_out, int out_size, void* d_ws, size_t ws_size,
                              hipStream_t stream) {
    const float* x   = (const float*)d_in[0];
    const int*   pp  = (const int*)d_in[1];
    float*       out = (float*)d_out;
    int rows = in_sizes[0] / COLS;           // 8192 (even)
    hipLaunchKernelGGL(intent_dropout_kernel, dim3(rows / 2), dim3(TPB), 0, stream,
                       x, pp, out);
}